// Round 1
// baseline (306.065 us; speedup 1.0000x reference)
//
#include <hip/hip_runtime.h>

// Biquad (direct-form-II-transposed) over [B=512, T=48000] fp32, per-channel coeffs.
// Chunked linear-recurrence scan:
//   pass1: per-chunk zero-state response v (state after L steps from s=0)
//   pass2: per-channel combine: Phi = A^L (binary pow), s_{c+1} = Phi*s_c + v_c
//   pass3: per-chunk exact replay from correct initial state, writing y.

#define T_LEN  48000
#define B_CH   512
#define CHUNKS 250
#define CLEN   192      // CHUNKS * CLEN == T_LEN; 192 floats = 768B (float4-aligned)
#define NTHREADS (B_CH * CHUNKS)

// ---------------------------------------------------------------- pass 1
__global__ __launch_bounds__(256) void k_chunk_state(
    const float* __restrict__ x,
    const float* __restrict__ b0, const float* __restrict__ b1,
    const float* __restrict__ b2,
    const float* __restrict__ a1, const float* __restrict__ a2,
    float2* __restrict__ vbuf)
{
    int tid = blockIdx.x * blockDim.x + threadIdx.x;
    if (tid >= NTHREADS) return;
    int b = tid / CHUNKS;

    float A1 = a1[b], A2 = a2[b];
    float B0 = b0[b], B1 = b1[b], B2 = b2[b];
    // substituted state update (y eliminated):
    //   z1' = (b1 - a1*b0)*x - a1*z1 + z2
    //   z2' = (b2 - a2*b0)*x - a2*z1
    float c1 = B1 - A1 * B0;
    float c2 = B2 - A2 * B0;

    const float4* xp = (const float4*)(x + (size_t)tid * CLEN);
    float z1 = 0.f, z2 = 0.f;
    #pragma unroll 4
    for (int i = 0; i < CLEN / 4; ++i) {
        float4 v = xp[i];
        float xn, nz1;
        xn = v.x; nz1 = c1*xn + z2 - A1*z1; z2 = c2*xn - A2*z1; z1 = nz1;
        xn = v.y; nz1 = c1*xn + z2 - A1*z1; z2 = c2*xn - A2*z1; z1 = nz1;
        xn = v.z; nz1 = c1*xn + z2 - A1*z1; z2 = c2*xn - A2*z1; z1 = nz1;
        xn = v.w; nz1 = c1*xn + z2 - A1*z1; z2 = c2*xn - A2*z1; z1 = nz1;
    }
    vbuf[tid] = make_float2(z1, z2);
}

// ---------------------------------------------------------------- pass 2
__global__ __launch_bounds__(256) void k_combine(
    const float* __restrict__ a1, const float* __restrict__ a2,
    const float2* __restrict__ vbuf, float2* __restrict__ sbuf)
{
    int b = blockIdx.x * blockDim.x + threadIdx.x;
    if (b >= B_CH) return;
    float A1 = a1[b], A2 = a2[b];

    // A = [[-a1, 1], [-a2, 0]];  Phi = A^CLEN via binary exponentiation
    float m00 = -A1, m01 = 1.f, m10 = -A2, m11 = 0.f;
    float p00 = 1.f, p01 = 0.f, p10 = 0.f, p11 = 1.f;
    int e = CLEN;
    while (e) {
        if (e & 1) {
            float t00 = p00*m00 + p01*m10;
            float t01 = p00*m01 + p01*m11;
            float t10 = p10*m00 + p11*m10;
            float t11 = p10*m01 + p11*m11;
            p00 = t00; p01 = t01; p10 = t10; p11 = t11;
        }
        e >>= 1;
        if (!e) break;
        float s00 = m00*m00 + m01*m10;
        float s01 = m00*m01 + m01*m11;
        float s10 = m10*m00 + m11*m10;
        float s11 = m10*m01 + m11*m11;
        m00 = s00; m01 = s01; m10 = s10; m11 = s11;
    }

    float z1 = 0.f, z2 = 0.f;
    int base = b * CHUNKS;
    for (int c = 0; c < CHUNKS; ++c) {
        sbuf[base + c] = make_float2(z1, z2);   // initial state for chunk c
        float2 v = vbuf[base + c];
        float nz1 = p00*z1 + p01*z2 + v.x;
        float nz2 = p10*z1 + p11*z2 + v.y;
        z1 = nz1; z2 = nz2;
    }
}

// ---------------------------------------------------------------- pass 3
__global__ __launch_bounds__(256) void k_apply(
    const float* __restrict__ x,
    const float* __restrict__ b0, const float* __restrict__ b1,
    const float* __restrict__ b2,
    const float* __restrict__ a1, const float* __restrict__ a2,
    const float2* __restrict__ sbuf,
    float* __restrict__ y)
{
    int tid = blockIdx.x * blockDim.x + threadIdx.x;
    if (tid >= NTHREADS) return;
    int b = tid / CHUNKS;

    float A1 = a1[b], A2 = a2[b];
    float B0 = b0[b], B1 = b1[b], B2 = b2[b];

    float2 s = sbuf[tid];
    float z1 = s.x, z2 = s.y;

    const float4* xp = (const float4*)(x + (size_t)tid * CLEN);
    float4*       yp = (float4*)(y + (size_t)tid * CLEN);

    #pragma unroll 4
    for (int i = 0; i < CLEN / 4; ++i) {
        float4 v = xp[i];
        float4 o;
        float xn, yn;
        xn = v.x; yn = B0*xn + z1; o.x = yn;
        { float nz1 = B1*xn - A1*yn + z2; z2 = B2*xn - A2*yn; z1 = nz1; }
        xn = v.y; yn = B0*xn + z1; o.y = yn;
        { float nz1 = B1*xn - A1*yn + z2; z2 = B2*xn - A2*yn; z1 = nz1; }
        xn = v.z; yn = B0*xn + z1; o.z = yn;
        { float nz1 = B1*xn - A1*yn + z2; z2 = B2*xn - A2*yn; z1 = nz1; }
        xn = v.w; yn = B0*xn + z1; o.w = yn;
        { float nz1 = B1*xn - A1*yn + z2; z2 = B2*xn - A2*yn; z1 = nz1; }
        yp[i] = o;
    }
}

// ---------------------------------------------------------------- launch
extern "C" void kernel_launch(void* const* d_in, const int* in_sizes, int n_in,
                              void* d_out, int out_size, void* d_ws, size_t ws_size,
                              hipStream_t stream) {
    const float* x  = (const float*)d_in[0];
    const float* b0 = (const float*)d_in[1];
    const float* b1 = (const float*)d_in[2];
    const float* b2 = (const float*)d_in[3];
    const float* a1 = (const float*)d_in[4];
    const float* a2 = (const float*)d_in[5];
    float* y = (float*)d_out;

    float2* vbuf = (float2*)d_ws;              // [B_CH*CHUNKS] zero-state responses
    float2* sbuf = vbuf + NTHREADS;            // [B_CH*CHUNKS] chunk initial states

    dim3 blk(256);
    dim3 grd((NTHREADS + 255) / 256);          // = 500 exactly

    k_chunk_state<<<grd, blk, 0, stream>>>(x, b0, b1, b2, a1, a2, vbuf);
    k_combine<<<dim3(2), blk, 0, stream>>>(a1, a2, vbuf, sbuf);
    k_apply<<<grd, blk, 0, stream>>>(x, b0, b1, b2, a1, a2, sbuf, y);
}

// Round 2
// 206.160 us; speedup vs baseline: 1.4846x; 1.4846x over previous
//
#include <hip/hip_runtime.h>

// Biquad DF2T over [B=512, T=48000] fp32, per-channel coeffs.
// Chunked linear-recurrence scan with LDS-staged coalescing:
//   pass1 (k_chunk_state): per-chunk zero-state response v (state after CLEN steps from 0)
//   pass2 (k_combine):     per-channel Kogge-Stone scan: s_{c+1} = Phi*s_c + v_c, Phi = A^CLEN
//   pass3 (k_apply):       per-chunk exact replay from correct initial state, writing y.

#define T_LEN  48000
#define B_CH   512
#define CHUNKS 500          // chunks per channel
#define CLEN   96           // CHUNKS * CLEN == T_LEN
#define NTH    (B_CH * CHUNKS)   // 256000 threads, 1000 blocks of 256
#define W      32           // time-tile width (CLEN % W == 0 -> 3 tiles)
#define STR    33           // padded LDS row stride: bank (lane+i)%32, conflict-free

// ---------------------------------------------------------------- pass 1
__global__ __launch_bounds__(256) void k_chunk_state(
    const float* __restrict__ x,
    const float* __restrict__ b0, const float* __restrict__ b1,
    const float* __restrict__ b2,
    const float* __restrict__ a1, const float* __restrict__ a2,
    float2* __restrict__ vbuf)
{
    __shared__ float lds[256 * STR];
    const int j     = threadIdx.x;
    const int chunk = blockIdx.x * 256 + j;
    const int b     = chunk / CHUNKS;

    const float A1 = a1[b], A2 = a2[b];
    const float B0 = b0[b], B1 = b1[b], B2 = b2[b];
    // y eliminated:  z1' = (b1-a1*b0)*x - a1*z1 + z2 ;  z2' = (b2-a2*b0)*x - a2*z1
    const float c1 = B1 - A1 * B0;
    const float c2 = B2 - A2 * B0;

    const int r = j >> 3, q = j & 7;          // fill mapping: 8 lanes per 128B row-segment
    float z1 = 0.f, z2 = 0.f;

    for (int tile = 0; tile < CLEN / W; ++tile) {
        const float* src = x + (size_t)blockIdx.x * 256 * CLEN + tile * W;
        #pragma unroll
        for (int p = 0; p < 8; ++p) {
            const int row = r + 32 * p;
            const float4 v = *(const float4*)(src + (size_t)row * CLEN + q * 4);
            float* d = &lds[row * STR + q * 4];
            d[0] = v.x; d[1] = v.y; d[2] = v.z; d[3] = v.w;
        }
        __syncthreads();
        const float* myrow = &lds[j * STR];
        #pragma unroll
        for (int i = 0; i < W; ++i) {
            const float xn = myrow[i];
            const float nz1 = c1 * xn + z2 - A1 * z1;
            z2 = c2 * xn - A2 * z1;
            z1 = nz1;
        }
        __syncthreads();
    }
    vbuf[chunk] = make_float2(z1, z2);
}

// ---------------------------------------------------------------- pass 2
// One block per channel; Kogge-Stone scan over CHUNKS affine transforms.
__global__ __launch_bounds__(512) void k_combine(
    const float* __restrict__ a1, const float* __restrict__ a2,
    const float2* __restrict__ vbuf, float2* __restrict__ sbuf)
{
    __shared__ float4 Pls[512];
    __shared__ float2 wls[512];
    const int b = blockIdx.x;
    const int t = threadIdx.x;

    const float A1 = a1[b], A2 = a2[b];

    // Phi = A^CLEN, A = [[-a1,1],[-a2,0]] (binary exponentiation, redundant per thread)
    float m00 = -A1, m01 = 1.f, m10 = -A2, m11 = 0.f;
    float f00 = 1.f, f01 = 0.f, f10 = 0.f, f11 = 1.f;
    int e = CLEN;
    while (e) {
        if (e & 1) {
            float t00 = f00*m00 + f01*m10, t01 = f00*m01 + f01*m11;
            float t10 = f10*m00 + f11*m10, t11 = f10*m01 + f11*m11;
            f00 = t00; f01 = t01; f10 = t10; f11 = t11;
        }
        e >>= 1;
        if (!e) break;
        float s00 = m00*m00 + m01*m10, s01 = m00*m01 + m01*m11;
        float s10 = m10*m00 + m11*m10, s11 = m10*m01 + m11*m11;
        m00 = s00; m01 = s01; m10 = s10; m11 = s11;
    }

    const bool act = (t < CHUNKS);
    float P00, P01, P10, P11, w0, w1;
    if (act) {
        P00 = f00; P01 = f01; P10 = f10; P11 = f11;
        float2 v = vbuf[(size_t)b * CHUNKS + t];
        w0 = v.x; w1 = v.y;
    } else {
        P00 = 1.f; P01 = 0.f; P10 = 0.f; P11 = 1.f; w0 = 0.f; w1 = 0.f;
    }

    for (int off = 1; off < CHUNKS; off <<= 1) {
        Pls[t] = make_float4(P00, P01, P10, P11);
        wls[t] = make_float2(w0, w1);
        __syncthreads();
        float n00 = P00, n01 = P01, n10 = P10, n11 = P11, nw0 = w0, nw1 = w1;
        if (act && t >= off) {
            const float4 E  = Pls[t - off];
            const float2 ew = wls[t - off];
            n00 = P00*E.x + P01*E.z;  n01 = P00*E.y + P01*E.w;
            n10 = P10*E.x + P11*E.z;  n11 = P10*E.y + P11*E.w;
            nw0 = P00*ew.x + P01*ew.y + w0;
            nw1 = P10*ew.x + P11*ew.y + w1;
        }
        __syncthreads();
        P00 = n00; P01 = n01; P10 = n10; P11 = n11; w0 = nw0; w1 = nw1;
    }

    // inclusive result w_t == s_{t+1}; exclusive shift:
    if (t == 0) sbuf[(size_t)b * CHUNKS] = make_float2(0.f, 0.f);
    if (act && t < CHUNKS - 1) sbuf[(size_t)b * CHUNKS + t + 1] = make_float2(w0, w1);
}

// ---------------------------------------------------------------- pass 3
__global__ __launch_bounds__(256) void k_apply(
    const float* __restrict__ x,
    const float* __restrict__ b0, const float* __restrict__ b1,
    const float* __restrict__ b2,
    const float* __restrict__ a1, const float* __restrict__ a2,
    const float2* __restrict__ sbuf,
    float* __restrict__ y)
{
    __shared__ float lds[256 * STR];
    const int j     = threadIdx.x;
    const int chunk = blockIdx.x * 256 + j;
    const int b     = chunk / CHUNKS;

    const float A1 = a1[b], A2 = a2[b];
    const float B0 = b0[b], B1 = b1[b], B2 = b2[b];

    const float2 s = sbuf[chunk];
    float z1 = s.x, z2 = s.y;

    const int r = j >> 3, q = j & 7;

    for (int tile = 0; tile < CLEN / W; ++tile) {
        const size_t base = (size_t)blockIdx.x * 256 * CLEN + tile * W;
        // fill: coalesced global -> LDS rows
        #pragma unroll
        for (int p = 0; p < 8; ++p) {
            const int row = r + 32 * p;
            const float4 v = *(const float4*)(x + base + (size_t)row * CLEN + q * 4);
            float* d = &lds[row * STR + q * 4];
            d[0] = v.x; d[1] = v.y; d[2] = v.z; d[3] = v.w;
        }
        __syncthreads();
        // compute in place: x row -> y row
        float* myrow = &lds[j * STR];
        #pragma unroll
        for (int i = 0; i < W; ++i) {
            const float xn = myrow[i];
            const float yn = B0 * xn + z1;
            myrow[i] = yn;
            const float nz1 = B1 * xn - A1 * yn + z2;
            z2 = B2 * xn - A2 * yn;
            z1 = nz1;
        }
        __syncthreads();
        // writeback: LDS rows -> coalesced global
        #pragma unroll
        for (int p = 0; p < 8; ++p) {
            const int row = r + 32 * p;
            const float* sp = &lds[row * STR + q * 4];
            float4 v;
            v.x = sp[0]; v.y = sp[1]; v.z = sp[2]; v.w = sp[3];
            *(float4*)(y + base + (size_t)row * CLEN + q * 4) = v;
        }
        __syncthreads();
    }
}

// ---------------------------------------------------------------- launch
extern "C" void kernel_launch(void* const* d_in, const int* in_sizes, int n_in,
                              void* d_out, int out_size, void* d_ws, size_t ws_size,
                              hipStream_t stream) {
    const float* x  = (const float*)d_in[0];
    const float* b0 = (const float*)d_in[1];
    const float* b1 = (const float*)d_in[2];
    const float* b2 = (const float*)d_in[3];
    const float* a1 = (const float*)d_in[4];
    const float* a2 = (const float*)d_in[5];
    float* y = (float*)d_out;

    float2* vbuf = (float2*)d_ws;       // [NTH] zero-state responses
    float2* sbuf = vbuf + NTH;          // [NTH] chunk initial states

    k_chunk_state<<<dim3(NTH / 256), dim3(256), 0, stream>>>(x, b0, b1, b2, a1, a2, vbuf);
    k_combine<<<dim3(B_CH), dim3(512), 0, stream>>>(a1, a2, vbuf, sbuf);
    k_apply<<<dim3(NTH / 256), dim3(256), 0, stream>>>(x, b0, b1, b2, a1, a2, sbuf, y);
}

// Round 3
// 190.799 us; speedup vs baseline: 1.6041x; 1.0805x over previous
//
#include <hip/hip_runtime.h>

// Biquad DF2T over [B=512, T=48000] fp32, per-channel coeffs.
// Single fused kernel: one block per channel, 512 threads.
// Per stage of 12000 samples:
//   1) coalesced float4 load -> LDS rows (stride 25 floats: 2-way bank alias, free)
//   2) 500 threads: zero-state response over own 24-sample subchunk
//   3) Kogge-Stone scan of affine transforms (Phi = A^24, w = local response)
//      combined with inter-stage carry -> true initial state per thread
//   4) replay subchunk exactly (reference arithmetic), overwrite LDS row with y
//   5) coalesced float4 writeback
// Traffic: x read once (98 MB), y written once (98 MB). No global scratch.

#define B_CH   512
#define T_LEN  48000
#define NSTAGE 4
#define STAGE  12000        // floats per stage (48 KB)
#define NACT   500          // active compute threads per block
#define L      24           // samples per thread per stage (NACT*L == STAGE)
#define STRIDE 25           // padded LDS row stride
#define NF4    (STAGE / 4)  // 3000 float4 per stage
#define F4ROW  (L / 4)      // 6 float4 per row

__global__ __launch_bounds__(512) void k_biquad_fused(
    const float* __restrict__ x,
    const float* __restrict__ b0, const float* __restrict__ b1,
    const float* __restrict__ b2,
    const float* __restrict__ a1, const float* __restrict__ a2,
    float* __restrict__ y)
{
    __shared__ float  xl[NACT * STRIDE];   // 12500 floats = 50 KB
    __shared__ float4 Pls[512];            // 8 KB
    __shared__ float2 wls[512];            // 4 KB

    const int b = blockIdx.x;
    const int t = threadIdx.x;

    const float A1 = a1[b], A2 = a2[b];
    const float B0 = b0[b], B1 = b1[b], B2 = b2[b];
    // y-eliminated state form: z1' = c1*x - a1*z1 + z2 ; z2' = c2*x - a2*z1
    const float c1 = B1 - A1 * B0;
    const float c2 = B2 - A2 * B0;

    // Phi = A^L, A = [[-a1,1],[-a2,0]] (binary exponentiation, per-thread redundant)
    float G00, G01, G10, G11;
    {
        float m00 = -A1, m01 = 1.f, m10 = -A2, m11 = 0.f;
        float f00 = 1.f, f01 = 0.f, f10 = 0.f, f11 = 1.f;
        int e = L;
        while (e) {
            if (e & 1) {
                float t00 = f00*m00 + f01*m10, t01 = f00*m01 + f01*m11;
                float t10 = f10*m00 + f11*m10, t11 = f10*m01 + f11*m11;
                f00 = t00; f01 = t01; f10 = t10; f11 = t11;
            }
            e >>= 1;
            if (!e) break;
            float s00 = m00*m00 + m01*m10, s01 = m00*m01 + m01*m11;
            float s10 = m10*m00 + m11*m10, s11 = m10*m01 + m11*m11;
            m00 = s00; m01 = s01; m10 = s10; m11 = s11;
        }
        G00 = f00; G01 = f01; G10 = f10; G11 = f11;
    }

    const float* xb = x + (size_t)b * T_LEN;
    float*       yb = y + (size_t)b * T_LEN;

    float cz1 = 0.f, cz2 = 0.f;            // inter-stage carry state

    for (int s = 0; s < NSTAGE; ++s) {
        const float* xs = xb + s * STAGE;
        float*       ys = yb + s * STAGE;

        // ---- 1) coalesced fill: global float4 -> padded LDS rows
        #pragma unroll
        for (int g = t; g < NF4; g += 512) {
            const float4 v = *(const float4*)(xs + 4 * g);
            const int own = g / F4ROW;
            const int off = (g - own * F4ROW) * 4;
            float* d = &xl[own * STRIDE + off];
            d[0] = v.x; d[1] = v.y; d[2] = v.z; d[3] = v.w;
        }
        __syncthreads();

        // ---- 2) local zero-state response over own subchunk
        float P00 = G00, P01 = G01, P10 = G10, P11 = G11, w0, w1;
        {
            float z1 = 0.f, z2 = 0.f;
            if (t < NACT) {
                const float* r = &xl[t * STRIDE];
                #pragma unroll 8
                for (int i = 0; i < L; ++i) {
                    const float xn = r[i];
                    const float nz1 = c1 * xn + z2 - A1 * z1;
                    z2 = c2 * xn - A2 * z1;
                    z1 = nz1;
                }
            }
            w0 = z1; w1 = z2;
        }
        if (t >= NACT) { P00 = 1.f; P01 = 0.f; P10 = 0.f; P11 = 1.f; w0 = 0.f; w1 = 0.f; }

        // ---- 3) Kogge-Stone inclusive scan over NACT affine transforms
        for (int off = 1; off < NACT; off <<= 1) {
            Pls[t] = make_float4(P00, P01, P10, P11);
            wls[t] = make_float2(w0, w1);
            __syncthreads();
            if (t >= off && t < NACT) {
                const float4 E  = Pls[t - off];
                const float2 ew = wls[t - off];
                const float n00 = P00*E.x + P01*E.z, n01 = P00*E.y + P01*E.w;
                const float n10 = P10*E.x + P11*E.z, n11 = P10*E.y + P11*E.w;
                w0 = P00*ew.x + P01*ew.y + w0;
                w1 = P10*ew.x + P11*ew.y + w1;
                P00 = n00; P01 = n01; P10 = n10; P11 = n11;
            }
            __syncthreads();
        }
        Pls[t] = make_float4(P00, P01, P10, P11);
        wls[t] = make_float2(w0, w1);
        __syncthreads();

        // initial state for this thread = exclusive prefix applied to carry
        float z1, z2;
        if (t == 0) { z1 = cz1; z2 = cz2; }
        else {
            const float4 E  = Pls[t - 1];
            const float2 ew = wls[t - 1];
            z1 = E.x * cz1 + E.y * cz2 + ew.x;
            z2 = E.z * cz1 + E.w * cz2 + ew.y;
        }
        // advance carry (all threads compute identically from element NACT-1)
        {
            const float4 E  = Pls[NACT - 1];
            const float2 ew = wls[NACT - 1];
            const float n1 = E.x * cz1 + E.y * cz2 + ew.x;
            const float n2 = E.z * cz1 + E.w * cz2 + ew.y;
            cz1 = n1; cz2 = n2;
        }

        // ---- 4) exact replay (reference arithmetic), overwrite row with y
        if (t < NACT) {
            float* r = &xl[t * STRIDE];
            #pragma unroll 8
            for (int i = 0; i < L; ++i) {
                const float xn = r[i];
                const float yn = B0 * xn + z1;
                r[i] = yn;
                const float nz1 = B1 * xn - A1 * yn + z2;
                z2 = B2 * xn - A2 * yn;
                z1 = nz1;
            }
        }
        __syncthreads();

        // ---- 5) coalesced writeback: padded LDS rows -> global float4
        #pragma unroll
        for (int g = t; g < NF4; g += 512) {
            const int own = g / F4ROW;
            const int off = (g - own * F4ROW) * 4;
            const float* sp = &xl[own * STRIDE + off];
            float4 v;
            v.x = sp[0]; v.y = sp[1]; v.z = sp[2]; v.w = sp[3];
            *(float4*)(ys + 4 * g) = v;
        }
        __syncthreads();
    }
}

extern "C" void kernel_launch(void* const* d_in, const int* in_sizes, int n_in,
                              void* d_out, int out_size, void* d_ws, size_t ws_size,
                              hipStream_t stream) {
    const float* x  = (const float*)d_in[0];
    const float* b0 = (const float*)d_in[1];
    const float* b1 = (const float*)d_in[2];
    const float* b2 = (const float*)d_in[3];
    const float* a1 = (const float*)d_in[4];
    const float* a2 = (const float*)d_in[5];
    float* y = (float*)d_out;

    k_biquad_fused<<<dim3(B_CH), dim3(512), 0, stream>>>(x, b0, b1, b2, a1, a2, y);
}